// Round 8
// baseline (138.942 us; speedup 1.0000x reference)
//
#include <hip/hip_runtime.h>

// Problem constants (match reference setup_inputs)
constexpr int B_IMG = 8;
constexpr int A_N   = 120000;
constexpr int C_N   = 80;
constexpr int M_N   = 32;

constexpr float ALPHA = 0.25f;

constexpr int BLK = 256;

// Stream kernel geometry: per image, SBLK blocks each own PERB contiguous float4
constexpr int SBLK  = 256;                    // stream blocks per image -> 2048 total
constexpr int F4IMG = A_N * C_N / 4;          // 2,400,000 float4 per image
constexpr int PERB  = F4IMG / SBLK;           // 9375 float4 per block (exact)
constexpr int U     = 8;                      // float4 in flight per thread
constexpr int FULLI = PERB / (BLK * U);       // 4 full batched iterations
constexpr int TOFF  = FULLI * BLK * U;        // 8192, tail is 1183 float4

// Assign kernel geometry: 1 anchor per thread
constexpr int ABLK  = (A_N + BLK - 1) / BLK;  // 469 blocks per image

typedef float f4v __attribute__((ext_vector_type(4)));

// ---------------------------------------------------------------------------
// Helpers
// ---------------------------------------------------------------------------
__device__ __forceinline__ float smooth_l1(float d) {
    d = fabsf(d);
    return (d <= (1.0f / 9.0f)) ? 4.5f * d * d : d - (0.5f / 9.0f);
}

__device__ __forceinline__ float loss_neg(float x) {
    // target == 0: (1-alpha) * p^2 * (-log(1-p))
    float p = fminf(fmaxf(x, 1e-4f), 0.9999f);
    return (1.0f - ALPHA) * p * p * (-__logf(1.0f - p));
}

__device__ __forceinline__ float loss_neg4(f4v v) {
    return loss_neg(v[0]) + loss_neg(v[1]) + loss_neg(v[2]) + loss_neg(v[3]);
}

__device__ __forceinline__ float loss_pos(float x) {
    // target == 1: alpha * (1-p)^2 * (-log(p))
    float p = fminf(fmaxf(x, 1e-4f), 0.9999f);
    float q = 1.0f - p;
    return ALPHA * q * q * (-__logf(p));
}

// ---------------------------------------------------------------------------
// Stream kernel: pure loss_neg reduction over the whole cls tensor.
// No LDS in loop, no masks, no divergence; ~48 VGPR -> 8 waves/SIMD.
// ---------------------------------------------------------------------------
__global__ __launch_bounds__(BLK, 8) void stream_kernel(
    const float* __restrict__ cls,    // [B,A,C]
    float* __restrict__ sPart)        // [B*SBLK]
{
    const int b = blockIdx.y;
    const int j = blockIdx.x;
    const int t = threadIdx.x;
    const f4v* __restrict__ src =
        (const f4v*)(cls + (size_t)b * A_N * C_N) + (size_t)j * PERB;

    float s = 0.0f;
    #pragma unroll 1
    for (int it = 0; it < FULLI; ++it) {
        f4v v[U];
        #pragma unroll
        for (int u = 0; u < U; ++u) v[u] = src[it * (BLK * U) + u * BLK + t];
        #pragma unroll
        for (int u = 0; u < U; ++u) s += loss_neg4(v[u]);
    }
    #pragma unroll 1
    for (int i = TOFF + t; i < PERB; i += BLK) s += loss_neg4(src[i]);

    #pragma unroll
    for (int off = 32; off; off >>= 1) s += __shfl_down(s, off);
    __shared__ float ws[BLK / 64];
    if ((t & 63) == 0) ws[t >> 6] = s;
    __syncthreads();
    if (t == 0) {
        float ss = 0.0f;
        #pragma unroll
        for (int w = 0; w < BLK / 64; ++w) ss += ws[w];
        sPart[b * SBLK + j] = ss;
    }
}

// ---------------------------------------------------------------------------
// Assign kernel: 1 anchor/thread. IoU argmax + reg loss + cls corrections:
//   ignored row  -> subtract its full loss_neg rowsum
//   positive row -> loss_pos(gt) - loss_neg(gt)
// ---------------------------------------------------------------------------
__global__ __launch_bounds__(BLK, 4) void assign_kernel(
    const float* __restrict__ cls,           // [B,A,C]
    const float* __restrict__ regressions,   // [B,A,4]
    const float* __restrict__ anchors,       // [A,4]
    const float* __restrict__ annotations,   // [B,M,5]
    float* __restrict__ corrPart,            // [B*ABLK]
    float* __restrict__ regPart,             // [B*ABLK]
    float* __restrict__ nposPart)            // [B*ABLK]
{
    const int b = blockIdx.y;
    const int a = blockIdx.x * BLK + threadIdx.x;
    const int t = threadIdx.x;
    const float* __restrict__ ann = annotations + (size_t)b * M_N * 5; // uniform

    float regl = 0.0f, corr = 0.0f;
    float pos = 0.0f;

    if (a < A_N) {
        const float4 anc = ((const float4*)anchors)[a];
        const float ax1 = anc.x, ay1 = anc.y, ax2 = anc.z, ay2 = anc.w;
        const float areaA = (ax2 - ax1) * (ay2 - ay1);

        // IoU argmax via cross-multiplication (1 division total)
        float bi = -1.0f, bu = 1.0f;
        int   bm = -1;
        #pragma unroll 2
        for (int m = 0; m < M_N; ++m) {
            const float gx1 = ann[m * 5 + 0];
            const float gy1 = ann[m * 5 + 1];
            const float gx2 = ann[m * 5 + 2];
            const float gy2 = ann[m * 5 + 3];
            const bool valid = (ann[m * 5 + 4] != -1.0f);
            float iw = fminf(ax2, gx2) - fmaxf(ax1, gx1);
            float ih = fminf(ay2, gy2) - fmaxf(ay1, gy1);
            iw = fmaxf(iw, 0.0f);
            ih = fmaxf(ih, 0.0f);
            const float inter = iw * ih;
            const float areaB = (gx2 - gx1) * (gy2 - gy1);
            const float ua = fmaxf(areaA + areaB - inter, 1e-8f);
            const bool better = valid && (inter * bu > bi * ua);
            if (better) { bi = inter; bu = ua; bm = m; }
        }
        const float iouMax = (bm >= 0) ? (bi / bu) : -1.0f;
        const bool positive = (iouMax >= 0.5f);
        const bool ignored  = (iouMax >= 0.4f) && !positive;

        if (positive) {
            pos = 1.0f;
            const float aw  = ax2 - ax1;
            const float ah  = ay2 - ay1;
            const float acx = ax1 + 0.5f * aw;
            const float acy = ay1 + 0.5f * ah;
            const float gx1 = ann[bm * 5 + 0];
            const float gy1 = ann[bm * 5 + 1];
            const float gx2 = ann[bm * 5 + 2];
            const float gy2 = ann[bm * 5 + 3];
            float gw = gx2 - gx1;
            float gh = gy2 - gy1;
            const float gcx = gx1 + 0.5f * gw;
            const float gcy = gy1 + 0.5f * gh;
            gw = fmaxf(gw, 1.0f);
            gh = fmaxf(gh, 1.0f);
            const float t0 = ((gcx - acx) / aw) * 10.0f;  // / 0.1
            const float t1 = ((gcy - acy) / ah) * 10.0f;
            const float t2 = __logf(gw / aw) * 5.0f;      // / 0.2
            const float t3 = __logf(gh / ah) * 5.0f;
            const float4 rg = ((const float4*)regressions)[(size_t)b * A_N + a];
            regl = smooth_l1(t0 - rg.x) + smooth_l1(t1 - rg.y) +
                   smooth_l1(t2 - rg.z) + smooth_l1(t3 - rg.w);

            const int code = (int)ann[bm * 5 + 4];
            const float x = cls[((size_t)b * A_N + a) * C_N + code];
            corr = loss_pos(x) - loss_neg(x);
        } else if (ignored) {
            // subtract this row's stream contribution
            const f4v* __restrict__ row =
                (const f4v*)(cls + ((size_t)b * A_N + a) * C_N);
            float rs = 0.0f;
            #pragma unroll 4
            for (int u = 0; u < C_N / 4; ++u) rs += loss_neg4(row[u]);
            corr = -rs;
        }
    }

    // block reduce
    float r = regl, p = pos, c = corr;
    #pragma unroll
    for (int off = 32; off; off >>= 1) {
        r += __shfl_down(r, off);
        p += __shfl_down(p, off);
        c += __shfl_down(c, off);
    }
    __shared__ float wr[BLK / 64], wp[BLK / 64], wc[BLK / 64];
    if ((t & 63) == 0) { wr[t >> 6] = r; wp[t >> 6] = p; wc[t >> 6] = c; }
    __syncthreads();
    if (t == 0) {
        float rr = 0.0f, pp = 0.0f, cc = 0.0f;
        #pragma unroll
        for (int w = 0; w < BLK / 64; ++w) { rr += wr[w]; pp += wp[w]; cc += wc[w]; }
        const int pidx = b * ABLK + blockIdx.x;
        corrPart[pidx] = cc;
        regPart[pidx]  = rr;
        nposPart[pidx] = pp;
    }
}

// ---------------------------------------------------------------------------
// Finalize: one wave per image -> two scalars
// ---------------------------------------------------------------------------
__global__ __launch_bounds__(64 * B_IMG) void finalize_kernel(
    const float* __restrict__ annotations,
    const float* __restrict__ sPart,
    const float* __restrict__ corrPart,
    const float* __restrict__ regPart,
    const float* __restrict__ nposPart,
    float* __restrict__ out)
{
    const int w    = threadIdx.x >> 6;   // image
    const int lane = threadIdx.x & 63;

    float s = 0.0f, c = 0.0f, r = 0.0f, p = 0.0f;
    for (int i = lane; i < SBLK; i += 64) s += sPart[w * SBLK + i];
    for (int i = lane; i < ABLK; i += 64) {
        const int idx = w * ABLK + i;
        c += corrPart[idx];
        r += regPart[idx];
        p += nposPart[idx];
    }
    #pragma unroll
    for (int off = 32; off; off >>= 1) {
        s += __shfl_down(s, off);
        c += __shfl_down(c, off);
        r += __shfl_down(r, off);
        p += __shfl_down(p, off);
    }

    __shared__ float sc[B_IMG], sr[B_IMG];
    if (lane == 0) {
        bool has = false;
        for (int m = 0; m < M_N; ++m)
            has = has || (annotations[(size_t)w * M_N * 5 + m * 5 + 4] != -1.0f);
        const float cl = (s + c) / fmaxf(p, 1.0f);
        const float rl = (p > 0.0f) ? r / (p * 4.0f) : 0.0f;
        sc[w] = has ? cl : 0.0f;
        sr[w] = has ? rl : 0.0f;
    }
    __syncthreads();
    if (threadIdx.x == 0) {
        float ca = 0.0f, ra = 0.0f;
        #pragma unroll
        for (int i = 0; i < B_IMG; ++i) { ca += sc[i]; ra += sr[i]; }
        out[0] = ca * (1.0f / B_IMG);
        out[1] = ra * (1.0f / B_IMG);
    }
}

// ---------------------------------------------------------------------------
// Launch
// ---------------------------------------------------------------------------
extern "C" void kernel_launch(void* const* d_in, const int* in_sizes, int n_in,
                              void* d_out, int out_size, void* d_ws, size_t ws_size,
                              hipStream_t stream) {
    const float* classifications = (const float*)d_in[0]; // [B,A,C]
    const float* regressions     = (const float*)d_in[1]; // [B,A,4]
    const float* anchors         = (const float*)d_in[2]; // [1,A,4]
    const float* annotations     = (const float*)d_in[3]; // [B,M,5]
    float* out = (float*)d_out;                           // [2]

    // Workspace: partials written exactly once per call -> no init pass
    float* sPart    = (float*)d_ws;                        // B*SBLK
    float* corrPart = sPart    + (size_t)B_IMG * SBLK;     // B*ABLK
    float* regPart  = corrPart + (size_t)B_IMG * ABLK;     // B*ABLK
    float* nposPart = regPart  + (size_t)B_IMG * ABLK;     // B*ABLK

    assign_kernel<<<dim3(ABLK, B_IMG), BLK, 0, stream>>>(
        classifications, regressions, anchors, annotations,
        corrPart, regPart, nposPart);

    stream_kernel<<<dim3(SBLK, B_IMG), BLK, 0, stream>>>(
        classifications, sPart);

    finalize_kernel<<<1, 64 * B_IMG, 0, stream>>>(
        annotations, sPart, corrPart, regPart, nposPart, out);
}

// Round 9
// 118.400 us; speedup vs baseline: 1.1735x; 1.1735x over previous
//
#include <hip/hip_runtime.h>

// Problem constants (match reference setup_inputs)
constexpr int B_IMG = 8;
constexpr int A_N   = 120000;
constexpr int C_N   = 80;
constexpr int M_N   = 32;

constexpr float ALPHA = 0.25f;

// Fused kernel geometry (empirically best: fused roles, APB=512, 1880 blocks)
constexpr int BLK  = 256;                          // threads per block (4 waves)
constexpr int APB  = 512;                          // anchors per block
constexpr int NBLK = (A_N + APB - 1) / APB;        // 235 blocks per image
constexpr int F4PA = C_N / 4;                      // 20 float4 per anchor
constexpr int U    = 4;                            // float4 per thread per buffer
constexpr int F4_PER_IT = BLK * U;                 // 1024 float4 per iteration
constexpr int NIT  = (APB * F4PA) / F4_PER_IT;     // 10 iterations
constexpr int ApT  = APB / BLK;                    // 2 anchors per thread

typedef float f4v __attribute__((ext_vector_type(4)));

// ---------------------------------------------------------------------------
// Helpers
// ---------------------------------------------------------------------------
__device__ __forceinline__ float smooth_l1(float d) {
    d = fabsf(d);
    return (d <= (1.0f / 9.0f)) ? 4.5f * d * d : d - (0.5f / 9.0f);
}

__device__ __forceinline__ float loss_neg(float x) {
    // target == 0: (1-alpha) * p^2 * (-log(1-p))
    float p = fminf(fmaxf(x, 1e-4f), 0.9999f);
    return (1.0f - ALPHA) * p * p * (-__logf(1.0f - p));
}

__device__ __forceinline__ float loss_neg4(f4v v) {
    return loss_neg(v[0]) + loss_neg(v[1]) + loss_neg(v[2]) + loss_neg(v[3]);
}

__device__ __forceinline__ float loss_pos(float x) {
    // target == 1: alpha * (1-p)^2 * (-log(p))
    float p = fminf(fmaxf(x, 1e-4f), 0.9999f);
    float q = 1.0f - p;
    return ALPHA * q * q * (-__logf(p));
}

// ---------------------------------------------------------------------------
// Fused kernel, stream-first:
//   phase S: pure loss_neg reduce over this block's 512 rows (no LDS, no sync)
//   phase A: IoU assignment for the same 512 anchors + algebraic corrections
//            (ignored row -> subtract rowsum; positive -> patch gt class)
// ---------------------------------------------------------------------------
__global__ __launch_bounds__(BLK, 4) void fused_kernel(
    const float* __restrict__ cls,           // [B,A,C]
    const float* __restrict__ regressions,   // [B,A,4]
    const float* __restrict__ anchors,       // [A,4]
    const float* __restrict__ annotations,   // [B,M,5]
    float* __restrict__ clsPart,             // [B*NBLK]  (stream + corrections)
    float* __restrict__ regPart,             // [B*NBLK]
    float* __restrict__ nposPart)            // [B*NBLK]
{
    const int b    = blockIdx.y;
    const int base = blockIdx.x * APB;                 // first anchor of block
    const int nA   = min(APB, A_N - base);             // anchors in this block
    const int t    = threadIdx.x;
    const int wave = t >> 6;
    const int lane = t & 63;
    const bool full = (nA == APB);

    const float* __restrict__ rowbase = cls + (size_t)(b * A_N + base) * C_N;
    const f4v* __restrict__ src = (const f4v*)rowbase;
    // per-wave contiguous 4KB segments: idx(it,u) = it*1024 + wave*256 + u*64 + lane
    const f4v* __restrict__ pw = src + wave * (64 * U) + lane;

    float csum = 0.0f;

    // ---- phase S: ping-pong double-buffered pure loss_neg stream ----
    if (full) {
        f4v vA[U], vB[U];
        #pragma unroll
        for (int u = 0; u < U; ++u) vA[u] = pw[u * 64];
        #pragma unroll
        for (int u = 0; u < U; ++u) vB[u] = pw[F4_PER_IT + u * 64];

        #pragma unroll 1
        for (int it2 = 0; it2 < NIT / 2; ++it2) {
            const int it = it2 * 2;
            float pa = 0.0f;
            #pragma unroll
            for (int u = 0; u < U; ++u) pa += loss_neg4(vA[u]);
            if (it + 2 < NIT) {
                #pragma unroll
                for (int u = 0; u < U; ++u)
                    vA[u] = pw[(it + 2) * F4_PER_IT + u * 64];
            }
            csum += pa;
            float pb = 0.0f;
            #pragma unroll
            for (int u = 0; u < U; ++u) pb += loss_neg4(vB[u]);
            if (it + 3 < NIT) {
                #pragma unroll
                for (int u = 0; u < U; ++u)
                    vB[u] = pw[(it + 3) * F4_PER_IT + u * 64];
            }
            csum += pb;
        }
    } else {
        const int nF4 = nA * F4PA;
        for (int idx = t; idx < nF4; idx += BLK)
            csum += loss_neg4(src[idx]);
    }

    // ---- phase A: assignment + corrections for this block's anchors ----
    const float* __restrict__ ann = annotations + (size_t)b * M_N * 5; // uniform
    float regl = 0.0f, pos = 0.0f;

    #pragma unroll 1
    for (int sIt = 0; sIt < ApT; ++sIt) {
        const int li = sIt * BLK + t;
        const int a  = base + li;
        if (li < nA) {
            const float4 anc = ((const float4*)anchors)[a];
            const float ax1 = anc.x, ay1 = anc.y, ax2 = anc.z, ay2 = anc.w;
            const float areaA = (ax2 - ax1) * (ay2 - ay1);

            // IoU argmax via cross-multiplication (1 division total)
            float bi = -1.0f, bu = 1.0f;
            int   bm = -1;
            #pragma unroll 2
            for (int m = 0; m < M_N; ++m) {
                const float gx1 = ann[m * 5 + 0];
                const float gy1 = ann[m * 5 + 1];
                const float gx2 = ann[m * 5 + 2];
                const float gy2 = ann[m * 5 + 3];
                const bool valid = (ann[m * 5 + 4] != -1.0f);
                float iw = fminf(ax2, gx2) - fmaxf(ax1, gx1);
                float ih = fminf(ay2, gy2) - fmaxf(ay1, gy1);
                iw = fmaxf(iw, 0.0f);
                ih = fmaxf(ih, 0.0f);
                const float inter = iw * ih;
                const float areaB = (gx2 - gx1) * (gy2 - gy1);
                const float ua = fmaxf(areaA + areaB - inter, 1e-8f);
                const bool better = valid && (inter * bu > bi * ua);
                if (better) { bi = inter; bu = ua; bm = m; }
            }
            const float iouMax = (bm >= 0) ? (bi / bu) : -1.0f;
            const bool positive = (iouMax >= 0.5f);
            const bool ignored  = (iouMax >= 0.4f) && !positive;

            if (positive) {
                pos += 1.0f;
                const float aw  = ax2 - ax1;
                const float ah  = ay2 - ay1;
                const float acx = ax1 + 0.5f * aw;
                const float acy = ay1 + 0.5f * ah;
                const float gx1 = ann[bm * 5 + 0];
                const float gy1 = ann[bm * 5 + 1];
                const float gx2 = ann[bm * 5 + 2];
                const float gy2 = ann[bm * 5 + 3];
                float gw = gx2 - gx1;
                float gh = gy2 - gy1;
                const float gcx = gx1 + 0.5f * gw;
                const float gcy = gy1 + 0.5f * gh;
                gw = fmaxf(gw, 1.0f);
                gh = fmaxf(gh, 1.0f);
                const float t0 = ((gcx - acx) / aw) * 10.0f;  // / 0.1
                const float t1 = ((gcy - acy) / ah) * 10.0f;
                const float t2 = __logf(gw / aw) * 5.0f;      // / 0.2
                const float t3 = __logf(gh / ah) * 5.0f;
                const float4 rg = ((const float4*)regressions)[(size_t)b * A_N + a];
                regl += smooth_l1(t0 - rg.x) + smooth_l1(t1 - rg.y) +
                        smooth_l1(t2 - rg.z) + smooth_l1(t3 - rg.w);

                const int code = (int)ann[bm * 5 + 4];
                const float x = rowbase[(size_t)li * C_N + code];
                csum += loss_pos(x) - loss_neg(x);
            } else if (ignored) {
                // subtract this row's stream contribution (row is L2/L3-hot)
                const f4v* __restrict__ row = (const f4v*)(rowbase + (size_t)li * C_N);
                float rs = 0.0f;
                #pragma unroll 4
                for (int u = 0; u < C_N / 4; ++u) rs += loss_neg4(row[u]);
                csum -= rs;
            }
        }
    }

    // ---- block reduce (deterministic, one write per block) ----
    float r = regl, p = pos, c = csum;
    #pragma unroll
    for (int off = 32; off; off >>= 1) {
        r += __shfl_down(r, off);
        p += __shfl_down(p, off);
        c += __shfl_down(c, off);
    }
    __shared__ float wr[BLK / 64], wp[BLK / 64], wc[BLK / 64];
    if (lane == 0) { wr[wave] = r; wp[wave] = p; wc[wave] = c; }
    __syncthreads();
    if (t == 0) {
        float rr = 0.0f, pp = 0.0f, cc = 0.0f;
        #pragma unroll
        for (int w = 0; w < BLK / 64; ++w) { rr += wr[w]; pp += wp[w]; cc += wc[w]; }
        const int pidx = b * NBLK + blockIdx.x;
        clsPart[pidx]  = cc;
        regPart[pidx]  = rr;
        nposPart[pidx] = pp;
    }
}

// ---------------------------------------------------------------------------
// Finalize: one wave per image, shfl reduce of NBLK partials -> two scalars
// ---------------------------------------------------------------------------
__global__ __launch_bounds__(64 * B_IMG) void finalize_kernel(
    const float* __restrict__ annotations,
    const float* __restrict__ clsPart,
    const float* __restrict__ regPart,
    const float* __restrict__ nposPart,
    float* __restrict__ out)
{
    const int w    = threadIdx.x >> 6;   // image
    const int lane = threadIdx.x & 63;

    float c = 0.0f, r = 0.0f, p = 0.0f;
    for (int i = lane; i < NBLK; i += 64) {
        const int idx = w * NBLK + i;
        c += clsPart[idx];
        r += regPart[idx];
        p += nposPart[idx];
    }
    #pragma unroll
    for (int off = 32; off; off >>= 1) {
        c += __shfl_down(c, off);
        r += __shfl_down(r, off);
        p += __shfl_down(p, off);
    }

    __shared__ float sc[B_IMG], sr[B_IMG];
    if (lane == 0) {
        bool has = false;
        for (int m = 0; m < M_N; ++m)
            has = has || (annotations[(size_t)w * M_N * 5 + m * 5 + 4] != -1.0f);
        const float cl = c / fmaxf(p, 1.0f);
        const float rl = (p > 0.0f) ? r / (p * 4.0f) : 0.0f;
        sc[w] = has ? cl : 0.0f;
        sr[w] = has ? rl : 0.0f;
    }
    __syncthreads();
    if (threadIdx.x == 0) {
        float ca = 0.0f, ra = 0.0f;
        #pragma unroll
        for (int i = 0; i < B_IMG; ++i) { ca += sc[i]; ra += sr[i]; }
        out[0] = ca * (1.0f / B_IMG);
        out[1] = ra * (1.0f / B_IMG);
    }
}

// ---------------------------------------------------------------------------
// Launch
// ---------------------------------------------------------------------------
extern "C" void kernel_launch(void* const* d_in, const int* in_sizes, int n_in,
                              void* d_out, int out_size, void* d_ws, size_t ws_size,
                              hipStream_t stream) {
    const float* classifications = (const float*)d_in[0]; // [B,A,C]
    const float* regressions     = (const float*)d_in[1]; // [B,A,4]
    const float* anchors         = (const float*)d_in[2]; // [1,A,4]
    const float* annotations     = (const float*)d_in[3]; // [B,M,5]
    float* out = (float*)d_out;                           // [2]

    // Workspace: partials written exactly once per call -> no init pass
    float* clsPart  = (float*)d_ws;                        // B*NBLK
    float* regPart  = clsPart + (size_t)B_IMG * NBLK;      // B*NBLK
    float* nposPart = regPart + (size_t)B_IMG * NBLK;      // B*NBLK

    fused_kernel<<<dim3(NBLK, B_IMG), BLK, 0, stream>>>(
        classifications, regressions, anchors, annotations,
        clsPart, regPart, nposPart);

    finalize_kernel<<<1, 64 * B_IMG, 0, stream>>>(
        annotations, clsPart, regPart, nposPart, out);
}

// Round 10
// 79.617 us; speedup vs baseline: 1.7451x; 1.4871x over previous
//
#include <hip/hip_runtime.h>

// Problem constants (match reference setup_inputs)
constexpr int B_IMG = 8;
constexpr int A_N   = 120000;
constexpr int C_N   = 80;
constexpr int M_N   = 32;

constexpr float ALPHA = 0.25f;

// Fused kernel geometry: 1 anchor per thread, mask-in-stream (proven fastest)
constexpr int BLK  = 256;                          // threads per block (4 waves)
constexpr int APB  = 256;                          // anchors per block
constexpr int NBLK = (A_N + APB - 1) / APB;        // 469 blocks per image
constexpr int F4PA = C_N / 4;                      // 20 float4 per anchor
constexpr int U    = 5;                            // float4 per thread per buffer
constexpr int F4_PER_IT = BLK * U;                 // 1280 float4 per iteration
constexpr int NIT  = (APB * F4PA) / F4_PER_IT;     // 4 iterations (even)

typedef float f4v __attribute__((ext_vector_type(4)));

// ---------------------------------------------------------------------------
// Helpers
// ---------------------------------------------------------------------------
__device__ __forceinline__ float smooth_l1(float d) {
    d = fabsf(d);
    return (d <= (1.0f / 9.0f)) ? 4.5f * d * d : d - (0.5f / 9.0f);
}

__device__ __forceinline__ float loss_neg(float x) {
    // target == 0: (1-alpha) * p^2 * (-log(1-p))
    float p = fminf(fmaxf(x, 1e-4f), 0.9999f);
    return (1.0f - ALPHA) * p * p * (-__logf(1.0f - p));
}

__device__ __forceinline__ float loss_neg4(f4v v) {
    return loss_neg(v[0]) + loss_neg(v[1]) + loss_neg(v[2]) + loss_neg(v[3]);
}

__device__ __forceinline__ float loss_pos(float x) {
    // target == 1: alpha * (1-p)^2 * (-log(p))
    float p = fminf(fmaxf(x, 1e-4f), 0.9999f);
    float q = 1.0f - p;
    return ALPHA * q * q * (-__logf(p));
}

// ---------------------------------------------------------------------------
// Fused kernel:
//   anc load -> prefetch (stays in flight) -> phase 1 IoU (scalar ann reads
//   only; no vector-load consumption => no vmcnt drain) -> phase 2 positive
//   corrections (reg loss + gt-class patch) -> sync -> masked ping-pong stream
// ---------------------------------------------------------------------------
__global__ __launch_bounds__(BLK, 4) void fused_kernel(
    const float* __restrict__ cls,           // [B,A,C]
    const float* __restrict__ regressions,   // [B,A,4]
    const float* __restrict__ anchors,       // [A,4]
    const float* __restrict__ annotations,   // [B,M,5]
    float* __restrict__ clsPart,             // [B*NBLK]
    float* __restrict__ regPart,             // [B*NBLK]
    float* __restrict__ nposPart)            // [B*NBLK]
{
    const int b    = blockIdx.y;
    const int base = blockIdx.x * APB;                 // first anchor of block
    const int nA   = min(APB, A_N - base);             // anchors in this block
    const int t    = threadIdx.x;
    const int wave = t >> 6;
    const int lane = t & 63;
    const int a    = base + t;                         // this thread's anchor
    const bool full = (nA == APB);
    const bool inA  = (t < nA);

    __shared__ float smask[APB];

    const float* __restrict__ rowbase = cls + (size_t)(b * A_N + base) * C_N;
    const f4v* __restrict__ src = (const f4v*)rowbase;
    // per-wave contiguous segments: idx(it,u) = it*1280 + wave*320 + u*64 + lane
    const f4v* __restrict__ pw = src + wave * (64 * U) + lane;
    const int widx0 = wave * (64 * U) + lane;

    // ---- 1) anchor load FIRST (so its waitcnt doesn't drain the prefetch) --
    float4 anc = make_float4(0.f, 0.f, 0.f, 0.f);
    if (inA) anc = ((const float4*)anchors)[a];

    // ---- 2) issue stream prefetch for iterations 0 and 1 ----
    f4v vA[U], vB[U];
    if (full) {
        #pragma unroll
        for (int u = 0; u < U; ++u) vA[u] = pw[u * 64];
        #pragma unroll
        for (int u = 0; u < U; ++u) vB[u] = pw[F4_PER_IT + u * 64];
    }

    // ---- phase 1: IoU argmax (scalar ann reads; anc already waited) ----
    const float* __restrict__ ann = annotations + (size_t)b * M_N * 5; // uniform
    int  bm = -1;
    bool positive = false, ignored = false;
    if (inA) {
        const float ax1 = anc.x, ay1 = anc.y, ax2 = anc.z, ay2 = anc.w;
        const float areaA = (ax2 - ax1) * (ay2 - ay1);
        float bi = -1.0f, bu = 1.0f;
        #pragma unroll 2
        for (int m = 0; m < M_N; ++m) {
            const float gx1 = ann[m * 5 + 0];
            const float gy1 = ann[m * 5 + 1];
            const float gx2 = ann[m * 5 + 2];
            const float gy2 = ann[m * 5 + 3];
            const bool valid = (ann[m * 5 + 4] != -1.0f);
            float iw = fminf(ax2, gx2) - fmaxf(ax1, gx1);
            float ih = fminf(ay2, gy2) - fmaxf(ay1, gy1);
            iw = fmaxf(iw, 0.0f);
            ih = fmaxf(ih, 0.0f);
            const float inter = iw * ih;
            const float areaB = (gx2 - gx1) * (gy2 - gy1);
            const float ua = fmaxf(areaA + areaB - inter, 1e-8f);
            const bool better = valid && (inter * bu > bi * ua);
            if (better) { bi = inter; bu = ua; bm = m; }
        }
        const float iouMax = (bm >= 0) ? (bi / bu) : -1.0f;
        positive = (iouMax >= 0.5f);
        ignored  = (iouMax >= 0.4f) && !positive;
    }
    smask[t] = (inA && !ignored) ? 1.0f : 0.0f;

    // ---- phase 2: positive corrections (vector loads land ~1k cyc in) ----
    float regl = 0.0f, csum = 0.0f;
    const float pos = positive ? 1.0f : 0.0f;
    if (positive) {
        const float ax1 = anc.x, ay1 = anc.y, ax2 = anc.z, ay2 = anc.w;
        const float aw  = ax2 - ax1;
        const float ah  = ay2 - ay1;
        const float acx = ax1 + 0.5f * aw;
        const float acy = ay1 + 0.5f * ah;
        const float gx1 = ann[bm * 5 + 0];
        const float gy1 = ann[bm * 5 + 1];
        const float gx2 = ann[bm * 5 + 2];
        const float gy2 = ann[bm * 5 + 3];
        float gw = gx2 - gx1;
        float gh = gy2 - gy1;
        const float gcx = gx1 + 0.5f * gw;
        const float gcy = gy1 + 0.5f * gh;
        gw = fmaxf(gw, 1.0f);
        gh = fmaxf(gh, 1.0f);
        const float t0 = ((gcx - acx) / aw) * 10.0f;  // / 0.1
        const float t1 = ((gcy - acy) / ah) * 10.0f;
        const float t2 = __logf(gw / aw) * 5.0f;      // / 0.2
        const float t3 = __logf(gh / ah) * 5.0f;
        const float4 rg = ((const float4*)regressions)[(size_t)b * A_N + a];
        regl = smooth_l1(t0 - rg.x) + smooth_l1(t1 - rg.y) +
               smooth_l1(t2 - rg.z) + smooth_l1(t3 - rg.w);

        const int code = (int)ann[bm * 5 + 4];
        const float x = rowbase[(size_t)t * C_N + code];
        csum += loss_pos(x) - loss_neg(x);
    }
    __syncthreads();

    // ---- phase 3: masked ping-pong stream (prefetch already in flight) ----
    if (full) {
        #pragma unroll 1
        for (int it2 = 0; it2 < NIT / 2; ++it2) {
            const int it = it2 * 2;
            float pa = 0.0f;
            #pragma unroll
            for (int u = 0; u < U; ++u) {
                const unsigned idx = (unsigned)(it * F4_PER_IT + widx0 + u * 64);
                pa += smask[idx / 20u] * loss_neg4(vA[u]);
            }
            if (it + 2 < NIT) {
                #pragma unroll
                for (int u = 0; u < U; ++u)
                    vA[u] = pw[(it + 2) * F4_PER_IT + u * 64];
            }
            csum += pa;
            float pb = 0.0f;
            #pragma unroll
            for (int u = 0; u < U; ++u) {
                const unsigned idx = (unsigned)((it + 1) * F4_PER_IT + widx0 + u * 64);
                pb += smask[idx / 20u] * loss_neg4(vB[u]);
            }
            if (it + 3 < NIT) {
                #pragma unroll
                for (int u = 0; u < U; ++u)
                    vB[u] = pw[(it + 3) * F4_PER_IT + u * 64];
            }
            csum += pb;
        }
    } else {
        const int nF4 = nA * F4PA;
        for (int idx = t; idx < nF4; idx += BLK)
            csum += smask[(unsigned)idx / 20u] * loss_neg4(src[idx]);
    }

    // ---- block reduce (deterministic, one write per block) ----
    float r = regl, p = pos, c = csum;
    #pragma unroll
    for (int off = 32; off; off >>= 1) {
        r += __shfl_down(r, off);
        p += __shfl_down(p, off);
        c += __shfl_down(c, off);
    }
    __shared__ float wr[BLK / 64], wp[BLK / 64], wc[BLK / 64];
    if (lane == 0) { wr[wave] = r; wp[wave] = p; wc[wave] = c; }
    __syncthreads();
    if (t == 0) {
        float rr = 0.0f, pp = 0.0f, cc = 0.0f;
        #pragma unroll
        for (int w = 0; w < BLK / 64; ++w) { rr += wr[w]; pp += wp[w]; cc += wc[w]; }
        const int pidx = b * NBLK + blockIdx.x;
        clsPart[pidx]  = cc;
        regPart[pidx]  = rr;
        nposPart[pidx] = pp;
    }
}

// ---------------------------------------------------------------------------
// Finalize: one wave per image, shfl reduce of NBLK partials -> two scalars
// ---------------------------------------------------------------------------
__global__ __launch_bounds__(64 * B_IMG) void finalize_kernel(
    const float* __restrict__ annotations,
    const float* __restrict__ clsPart,
    const float* __restrict__ regPart,
    const float* __restrict__ nposPart,
    float* __restrict__ out)
{
    const int w    = threadIdx.x >> 6;   // image
    const int lane = threadIdx.x & 63;

    float c = 0.0f, r = 0.0f, p = 0.0f;
    for (int i = lane; i < NBLK; i += 64) {
        const int idx = w * NBLK + i;
        c += clsPart[idx];
        r += regPart[idx];
        p += nposPart[idx];
    }
    #pragma unroll
    for (int off = 32; off; off >>= 1) {
        c += __shfl_down(c, off);
        r += __shfl_down(r, off);
        p += __shfl_down(p, off);
    }

    __shared__ float sc[B_IMG], sr[B_IMG];
    if (lane == 0) {
        bool has = false;
        for (int m = 0; m < M_N; ++m)
            has = has || (annotations[(size_t)w * M_N * 5 + m * 5 + 4] != -1.0f);
        const float cl = c / fmaxf(p, 1.0f);
        const float rl = (p > 0.0f) ? r / (p * 4.0f) : 0.0f;
        sc[w] = has ? cl : 0.0f;
        sr[w] = has ? rl : 0.0f;
    }
    __syncthreads();
    if (threadIdx.x == 0) {
        float ca = 0.0f, ra = 0.0f;
        #pragma unroll
        for (int i = 0; i < B_IMG; ++i) { ca += sc[i]; ra += sr[i]; }
        out[0] = ca * (1.0f / B_IMG);
        out[1] = ra * (1.0f / B_IMG);
    }
}

// ---------------------------------------------------------------------------
// Launch
// ---------------------------------------------------------------------------
extern "C" void kernel_launch(void* const* d_in, const int* in_sizes, int n_in,
                              void* d_out, int out_size, void* d_ws, size_t ws_size,
                              hipStream_t stream) {
    const float* classifications = (const float*)d_in[0]; // [B,A,C]
    const float* regressions     = (const float*)d_in[1]; // [B,A,4]
    const float* anchors         = (const float*)d_in[2]; // [1,A,4]
    const float* annotations     = (const float*)d_in[3]; // [B,M,5]
    float* out = (float*)d_out;                           // [2]

    // Workspace: partials written exactly once per call -> no init pass
    float* clsPart  = (float*)d_ws;                        // B*NBLK
    float* regPart  = clsPart + (size_t)B_IMG * NBLK;      // B*NBLK
    float* nposPart = regPart + (size_t)B_IMG * NBLK;      // B*NBLK

    fused_kernel<<<dim3(NBLK, B_IMG), BLK, 0, stream>>>(
        classifications, regressions, anchors, annotations,
        clsPart, regPart, nposPart);

    finalize_kernel<<<1, 64 * B_IMG, 0, stream>>>(
        annotations, clsPart, regPart, nposPart, out);
}